// Round 1
// baseline (202.246 us; speedup 1.0000x reference)
//
#include <hip/hip_runtime.h>

#define IMG_H 512
#define IMG_W 512
#define HW (IMG_H * IMG_W)
#define NB 32
#define ROWS 16
#define STRIPS (IMG_H / ROWS)   // 32

// Workspace layout (doubles first, then histogram):
//   acc[0..31]    lap_sum
//   acc[32..63]   lap_sumsq
//   acc[64..95]   depth_n
//   acc[96..127]  depth_sum
//   acc[128..159] depth_sumsq
//   hist: 32*256 uint at byte offset 160*8
#define ACC_DOUBLES 160
#define WS_BYTES (ACC_DOUBLES * 8 + NB * 256 * 4)

__device__ inline void wave_reduce2(double& a, double& b) {
    for (int off = 32; off > 0; off >>= 1) {
        a += __shfl_down(a, off, 64);
        b += __shfl_down(b, off, 64);
    }
}

__global__ __launch_bounds__(256) void rgb_kernel(
    const float* __restrict__ rgb,
    double* __restrict__ lap_sum, double* __restrict__ lap_sq,
    unsigned int* __restrict__ hist)
{
    __shared__ float g[ROWS + 2][IMG_W];
    __shared__ unsigned int lh[256];
    __shared__ double r1s[4], r2s[4];

    const int t = threadIdx.x;
    const int b = blockIdx.y;
    const int row0 = blockIdx.x * ROWS;

    lh[t] = 0u;

    const float* rp = rgb + (size_t)b * 3 * HW;
    const float* gp = rp + HW;
    const float* bp = gp + HW;

    // Load gray strip (with 1-row halo, zero outside image) into LDS.
    const int c0 = t * 2;
    for (int j = 0; j < ROWS + 2; ++j) {
        const int gr = row0 + j - 1;
        float gx = 0.f, gy = 0.f;
        if (gr >= 0 && gr < IMG_H) {
            const size_t o = (size_t)gr * IMG_W + c0;
            const float2 r2 = *(const float2*)(rp + o);
            const float2 g2 = *(const float2*)(gp + o);
            const float2 b2 = *(const float2*)(bp + o);
            gx = 0.299f * r2.x + 0.587f * g2.x + 0.114f * b2.x;
            gy = 0.299f * r2.y + 0.587f * g2.y + 0.114f * b2.y;
        }
        g[j][c0] = gx;
        g[j][c0 + 1] = gy;
    }
    __syncthreads();

    // Laplacian moments + histogram over the 16 owned rows.
    float s1 = 0.f, s2 = 0.f;
    for (int i = 0; i < ROWS * IMG_W / 256; ++i) {
        const int p = i * 256 + t;
        const int r = (p >> 9) + 1;     // LDS row (1..16)
        const int c = p & (IMG_W - 1);
        const float center = g[r][c];
        float lap = g[r - 1][c] + g[r + 1][c] - 4.f * center;
        lap += (c > 0) ? g[r][c - 1] : 0.f;
        lap += (c < IMG_W - 1) ? g[r][c + 1] : 0.f;
        s1 += lap;
        s2 += lap * lap;
        const float v = fminf(fmaxf(center * 255.f, 0.f), 255.f);
        atomicAdd(&lh[(int)v], 1u);
    }

    double d1 = (double)s1, d2 = (double)s2;
    wave_reduce2(d1, d2);
    const int wid = t >> 6, lane = t & 63;
    if (lane == 0) { r1s[wid] = d1; r2s[wid] = d2; }
    __syncthreads();   // covers lh atomics and r1s/r2s writes

    atomicAdd(&hist[b * 256 + t], lh[t]);
    if (t == 0) {
        atomicAdd(&lap_sum[b], r1s[0] + r1s[1] + r1s[2] + r1s[3]);
        atomicAdd(&lap_sq[b],  r2s[0] + r2s[1] + r2s[2] + r2s[3]);
    }
}

__global__ __launch_bounds__(256) void depth_kernel(
    const float* __restrict__ depth,
    double* __restrict__ dn, double* __restrict__ dsum, double* __restrict__ dsq)
{
    __shared__ double rns[4], rss[4], rqs[4];
    const int t = threadIdx.x;
    const int b = blockIdx.y;
    const size_t base = (size_t)b * HW + (size_t)blockIdx.x * (HW / 32);
    const float4* p4 = (const float4*)(depth + base);

    float n = 0.f, s = 0.f, q = 0.f;
    for (int i = 0; i < 8; ++i) {
        const float4 v = p4[i * 256 + t];
        if (v.x > 0.f) { n += 1.f; s += v.x; q += v.x * v.x; }
        if (v.y > 0.f) { n += 1.f; s += v.y; q += v.y * v.y; }
        if (v.z > 0.f) { n += 1.f; s += v.z; q += v.z * v.z; }
        if (v.w > 0.f) { n += 1.f; s += v.w; q += v.w * v.w; }
    }

    double dn_ = (double)n, ds_ = (double)s, dq_ = (double)q;
    for (int off = 32; off > 0; off >>= 1) {
        dn_ += __shfl_down(dn_, off, 64);
        ds_ += __shfl_down(ds_, off, 64);
        dq_ += __shfl_down(dq_, off, 64);
    }
    const int wid = t >> 6, lane = t & 63;
    if (lane == 0) { rns[wid] = dn_; rss[wid] = ds_; rqs[wid] = dq_; }
    __syncthreads();
    if (t == 0) {
        atomicAdd(&dn[b],   rns[0] + rns[1] + rns[2] + rns[3]);
        atomicAdd(&dsum[b], rss[0] + rss[1] + rss[2] + rss[3]);
        atomicAdd(&dsq[b],  rqs[0] + rqs[1] + rqs[2] + rqs[3]);
    }
}

__global__ void final_kernel(
    const double* __restrict__ acc,
    const unsigned int* __restrict__ hist,
    float* __restrict__ out)
{
    const int b = threadIdx.x;
    if (b >= NB) return;
    const double N = (double)HW;

    // entropy
    double e = 0.0;
    for (int k = 0; k < 256; ++k) {
        const float p = (float)hist[b * 256 + k] * (1.0f / (float)HW);
        e += (double)(p * log2f(p + 1e-4f));
    }
    const double entropy = -e;

    // laplace variance (ddof=1)
    const double ls = acc[b], lq = acc[32 + b];
    const double lvar = (lq - ls * ls / N) / (N - 1.0);
    const double clarity = lvar / (1000.0 + 1e-4);
    const double uniformity = 1.0 / (entropy + 1e-4);
    const double rgb_conf = 0.5 * (clarity + uniformity);

    // depth stats
    const double n = acc[64 + b], s = acc[96 + b], q = acc[128 + b];
    const double mean = s / fmax(n, 1.0);
    const double sq = q - 2.0 * mean * s + mean * mean * n;
    const double var = sq / fmax(n - 1.0, 1.0);
    const double stdd = sqrt(fmax(var, 0.0));
    const double noise = (n > 0.0) ? stdd : 1.0;
    const double density = n / N;
    const double depth_conf = 0.5 * (density / (10000.0 + 1e-4) + 1.0 / (noise + 1e-4));

    const double denom = rgb_conf + depth_conf + 1e-4;
    out[b]      = (float)(rgb_conf / denom);
    out[NB + b] = (float)(depth_conf / denom);
}

extern "C" void kernel_launch(void* const* d_in, const int* in_sizes, int n_in,
                              void* d_out, int out_size, void* d_ws, size_t ws_size,
                              hipStream_t stream) {
    const float* rgb   = (const float*)d_in[0];
    const float* depth = (const float*)d_in[1];
    float* out = (float*)d_out;

    double* acc = (double*)d_ws;
    unsigned int* hist = (unsigned int*)((char*)d_ws + ACC_DOUBLES * 8);

    hipMemsetAsync(d_ws, 0, WS_BYTES, stream);

    rgb_kernel<<<dim3(STRIPS, NB), 256, 0, stream>>>(rgb, acc, acc + 32, hist);
    depth_kernel<<<dim3(32, NB), 256, 0, stream>>>(depth, acc + 64, acc + 96, acc + 128);
    final_kernel<<<1, 64, 0, stream>>>(acc, hist, out);
}

// Round 2
// 192.836 us; speedup vs baseline: 1.0488x; 1.0488x over previous
//
#include <hip/hip_runtime.h>

#define IMG_H 512
#define IMG_W 512
#define HW (IMG_H * IMG_W)
#define NB 32
#define ROWS 16
#define STRIPS (IMG_H / ROWS)   // 32

// Workspace layout (doubles first, then histogram):
//   acc[0..31]    lap_sum
//   acc[32..63]   lap_sumsq
//   acc[64..95]   depth_n
//   acc[96..127]  depth_sum
//   acc[128..159] depth_sumsq
//   hist: 32*256 uint at byte offset 160*8
#define ACC_DOUBLES 160
#define WS_BYTES (ACC_DOUBLES * 8 + NB * 256 * 4)

// Fused kernel: block (s, b) handles rgb strip s AND depth chunk s of batch b.
// Grid 32x32 = 1024 blocks = 4 blocks/CU exactly (LDS-limited at ~38KB).
__global__ __launch_bounds__(256, 4) void fused_kernel(
    const float* __restrict__ rgb, const float* __restrict__ depth,
    double* __restrict__ acc, unsigned int* __restrict__ hist)
{
    __shared__ float g[ROWS + 2][IMG_W];      // 36864 B
    __shared__ unsigned int lh[256];
    __shared__ double red[4][5];

    const int t = threadIdx.x;
    const int b = blockIdx.y;
    const int s = blockIdx.x;
    const int row0 = s * ROWS;

    lh[t] = 0u;

    // ---- issue depth chunk loads first (latency hides under gray staging) ----
    const float4* dp = (const float4*)(depth + (size_t)b * HW + (size_t)s * (HW / STRIPS));
    float4 dv[8];
    #pragma unroll
    for (int i = 0; i < 8; ++i) dv[i] = dp[i * 256 + t];

    // ---- stage gray strip (rows row0-1 .. row0+16, zero outside) via float4 ----
    const float* rp = rgb + (size_t)b * 3 * HW;
    const int half = t >> 7;                 // 0/1: which row of the pair
    const int c4 = (t & 127) << 2;           // column (float4 granularity)
    #pragma unroll
    for (int j = 0; j < 9; ++j) {
        const int lr = 2 * j + half;         // LDS row 0..17
        const int gr = row0 + lr - 1;
        float4 gv = {0.f, 0.f, 0.f, 0.f};
        if (gr >= 0 && gr < IMG_H) {
            const size_t o = (size_t)gr * IMG_W + c4;
            const float4 r4 = *(const float4*)(rp + o);
            const float4 g4 = *(const float4*)(rp + HW + o);
            const float4 b4 = *(const float4*)(rp + 2 * HW + o);
            gv.x = 0.299f * r4.x + 0.587f * g4.x + 0.114f * b4.x;
            gv.y = 0.299f * r4.y + 0.587f * g4.y + 0.114f * b4.y;
            gv.z = 0.299f * r4.z + 0.587f * g4.z + 0.114f * b4.z;
            gv.w = 0.299f * r4.w + 0.587f * g4.w + 0.114f * b4.w;
        }
        *(float4*)&g[lr][c4] = gv;
    }

    // ---- accumulate depth stats (data already in registers) ----
    float dnf = 0.f, dsf = 0.f, dqf = 0.f;
    #pragma unroll
    for (int i = 0; i < 8; ++i) {
        const float4 v = dv[i];
        if (v.x > 0.f) { dnf += 1.f; dsf += v.x; dqf += v.x * v.x; }
        if (v.y > 0.f) { dnf += 1.f; dsf += v.y; dqf += v.y * v.y; }
        if (v.z > 0.f) { dnf += 1.f; dsf += v.z; dqf += v.z * v.z; }
        if (v.w > 0.f) { dnf += 1.f; dsf += v.w; dqf += v.w * v.w; }
    }

    __syncthreads();

    // ---- Laplacian moments + histogram, vectorized LDS reads ----
    float s1 = 0.f, s2 = 0.f;
    #pragma unroll
    for (int i = 0; i < 8; ++i) {
        const int gi = i * 256 + t;          // 2048 float4-groups total
        const int r = (gi >> 7) + 1;         // LDS row 1..16
        const int c = (gi & 127) << 2;       // column
        const float4 ce = *(const float4*)&g[r][c];
        const float4 up = *(const float4*)&g[r - 1][c];
        const float4 dn = *(const float4*)&g[r + 1][c];
        const float lf = (c > 0) ? g[r][c - 1] : 0.f;
        const float rt = (c < IMG_W - 4) ? g[r][c + 4] : 0.f;
        float4 lap;
        lap.x = up.x + dn.x + lf   + ce.y - 4.f * ce.x;
        lap.y = up.y + dn.y + ce.x + ce.z - 4.f * ce.y;
        lap.z = up.z + dn.z + ce.y + ce.w - 4.f * ce.z;
        lap.w = up.w + dn.w + ce.z + rt   - 4.f * ce.w;
        s1 += lap.x + lap.y + lap.z + lap.w;
        s2 += lap.x * lap.x + lap.y * lap.y + lap.z * lap.z + lap.w * lap.w;
        atomicAdd(&lh[(int)fminf(fmaxf(ce.x * 255.f, 0.f), 255.f)], 1u);
        atomicAdd(&lh[(int)fminf(fmaxf(ce.y * 255.f, 0.f), 255.f)], 1u);
        atomicAdd(&lh[(int)fminf(fmaxf(ce.z * 255.f, 0.f), 255.f)], 1u);
        atomicAdd(&lh[(int)fminf(fmaxf(ce.w * 255.f, 0.f), 255.f)], 1u);
    }

    // ---- block reduction of the 5 scalars ----
    double z0 = (double)s1, z1 = (double)s2, z2 = (double)dnf, z3 = (double)dsf, z4 = (double)dqf;
    for (int off = 32; off > 0; off >>= 1) {
        z0 += __shfl_down(z0, off, 64);
        z1 += __shfl_down(z1, off, 64);
        z2 += __shfl_down(z2, off, 64);
        z3 += __shfl_down(z3, off, 64);
        z4 += __shfl_down(z4, off, 64);
    }
    const int wid = t >> 6, lane = t & 63;
    if (lane == 0) {
        red[wid][0] = z0; red[wid][1] = z1; red[wid][2] = z2;
        red[wid][3] = z3; red[wid][4] = z4;
    }
    __syncthreads();   // covers lh atomics and red[] writes

    atomicAdd(&hist[b * 256 + t], lh[t]);
    if (t < 5) {
        const double v = red[0][t] + red[1][t] + red[2][t] + red[3][t];
        atomicAdd(&acc[t * 32 + b], v);
    }
}

__global__ __launch_bounds__(256) void final_kernel(
    const double* __restrict__ acc,
    const unsigned int* __restrict__ hist,
    float* __restrict__ out)
{
    __shared__ float part[256];
    const int t = threadIdx.x;
    const int b = t >> 3;        // 0..31
    const int sl = t & 7;        // 8 slices of 32 bins
    float e = 0.f;
    #pragma unroll
    for (int i = 0; i < 32; ++i) {
        const float p = (float)hist[b * 256 + sl * 32 + i] * (1.0f / (float)HW);
        e += p * log2f(p + 1e-4f);
    }
    part[t] = e;
    __syncthreads();

    if (t < NB) {
        float es = 0.f;
        #pragma unroll
        for (int i = 0; i < 8; ++i) es += part[t * 8 + i];
        const double entropy = -(double)es;
        const double N = (double)HW;

        const double ls = acc[t], lq = acc[32 + t];
        const double lvar = (lq - ls * ls / N) / (N - 1.0);
        const double clarity = lvar / (1000.0 + 1e-4);
        const double uniformity = 1.0 / (entropy + 1e-4);
        const double rgb_conf = 0.5 * (clarity + uniformity);

        const double n = acc[64 + t], sdep = acc[96 + t], q = acc[128 + t];
        const double mean = sdep / fmax(n, 1.0);
        const double sq = q - 2.0 * mean * sdep + mean * mean * n;
        const double var = sq / fmax(n - 1.0, 1.0);
        const double stdd = sqrt(fmax(var, 0.0));
        const double noise = (n > 0.0) ? stdd : 1.0;
        const double density = n / N;
        const double depth_conf = 0.5 * (density / (10000.0 + 1e-4) + 1.0 / (noise + 1e-4));

        const double denom = rgb_conf + depth_conf + 1e-4;
        out[t]      = (float)(rgb_conf / denom);
        out[NB + t] = (float)(depth_conf / denom);
    }
}

extern "C" void kernel_launch(void* const* d_in, const int* in_sizes, int n_in,
                              void* d_out, int out_size, void* d_ws, size_t ws_size,
                              hipStream_t stream) {
    const float* rgb   = (const float*)d_in[0];
    const float* depth = (const float*)d_in[1];
    float* out = (float*)d_out;

    double* acc = (double*)d_ws;
    unsigned int* hist = (unsigned int*)((char*)d_ws + ACC_DOUBLES * 8);

    hipMemsetAsync(d_ws, 0, WS_BYTES, stream);

    fused_kernel<<<dim3(STRIPS, NB), 256, 0, stream>>>(rgb, depth, acc, hist);
    final_kernel<<<1, 256, 0, stream>>>(acc, hist, out);
}

// Round 3
// 178.825 us; speedup vs baseline: 1.1310x; 1.0784x over previous
//
#include <hip/hip_runtime.h>

#define IMG_H 512
#define IMG_W 512
#define HW (IMG_H * IMG_W)
#define NB 32
#define STRIPS 16           // blocks per image; block = 4 waves x 8 rows = 32 rows
#define RPW 8               // rows per wave

// Workspace layout (doubles first, then histogram):
//   acc[0..31]    lap_sum     acc[32..63]  lap_sumsq
//   acc[64..95]   depth_n     acc[96..127] depth_sum   acc[128..159] depth_sumsq
//   hist: 32*256 uint at byte offset 160*8
#define ACC_DOUBLES 160
#define WS_BYTES (ACC_DOUBLES * 8 + NB * 256 * 4)

struct Row6 { float4 a0, a1, b0, b1, c0, c1; };

__device__ inline Row6 load_row(const float* __restrict__ rp, int r, int c0) {
    Row6 x;
    if ((unsigned)r < IMG_H) {          // wave-uniform branch
        const size_t o = (size_t)r * IMG_W + c0;
        x.a0 = *(const float4*)(rp + o);
        x.a1 = *(const float4*)(rp + o + 4);
        x.b0 = *(const float4*)(rp + HW + o);
        x.b1 = *(const float4*)(rp + HW + o + 4);
        x.c0 = *(const float4*)(rp + 2 * HW + o);
        x.c1 = *(const float4*)(rp + 2 * HW + o + 4);
    } else {
        const float4 z = {0.f, 0.f, 0.f, 0.f};
        x.a0 = x.a1 = x.b0 = x.b1 = x.c0 = x.c1 = z;
    }
    return x;
}

__device__ inline void to_gray(const Row6& x, float g[8]) {
    g[0] = 0.299f * x.a0.x + 0.587f * x.b0.x + 0.114f * x.c0.x;
    g[1] = 0.299f * x.a0.y + 0.587f * x.b0.y + 0.114f * x.c0.y;
    g[2] = 0.299f * x.a0.z + 0.587f * x.b0.z + 0.114f * x.c0.z;
    g[3] = 0.299f * x.a0.w + 0.587f * x.b0.w + 0.114f * x.c0.w;
    g[4] = 0.299f * x.a1.x + 0.587f * x.b1.x + 0.114f * x.c1.x;
    g[5] = 0.299f * x.a1.y + 0.587f * x.b1.y + 0.114f * x.c1.y;
    g[6] = 0.299f * x.a1.z + 0.587f * x.b1.z + 0.114f * x.c1.z;
    g[7] = 0.299f * x.a1.w + 0.587f * x.b1.w + 0.114f * x.c1.w;
}

// Barrier-free streaming: wave w of block (s,b) owns rows [s*32 + w*8, +8),
// lane owns 8 consecutive columns. prev/cur/next gray rows live in registers;
// horizontal neighbors via shuffle. Depth chunk interleaved into the same loop.
__global__ __launch_bounds__(256) void fused_kernel(
    const float* __restrict__ rgb, const float* __restrict__ depth,
    double* __restrict__ acc, unsigned int* __restrict__ hist)
{
    __shared__ unsigned int lh[4][256];
    __shared__ double red[4][5];

    const int t = threadIdx.x;
    const int b = blockIdx.y;
    const int s = blockIdx.x;
    const int lane = t & 63;
    const int w = t >> 6;

    #pragma unroll
    for (int i = 0; i < 4; ++i) lh[i][t & 255] = 0u;   // t in [0,256): init all 4 copies
    __syncthreads();

    const float* rp = rgb + (size_t)b * 3 * HW;
    const int rb = s * 32 + w * RPW;      // first owned row
    const int c0 = lane * 8;              // first owned column

    const float4* dp = (const float4*)(depth + (size_t)b * HW + (size_t)s * (HW / STRIPS));

    float gp[8], gc[8], gn[8];
    Row6 st0 = load_row(rp, rb - 1, c0);
    Row6 st1 = load_row(rp, rb, c0);
    to_gray(st0, gp);
    to_gray(st1, gc);

    float s1 = 0.f, s2 = 0.f;
    float dnf = 0.f, dsf = 0.f, dqf = 0.f;

    #pragma unroll
    for (int r = 0; r < RPW; ++r) {
        const Row6 nx = load_row(rp, rb + r + 1, c0);
        const float4 d0 = dp[(2 * r) * 256 + t];
        const float4 d1 = dp[(2 * r + 1) * 256 + t];
        to_gray(nx, gn);

        float lf = __shfl_up(gc[7], 1, 64);
        if (lane == 0) lf = 0.f;
        float rt = __shfl_down(gc[0], 1, 64);
        if (lane == 63) rt = 0.f;

        #pragma unroll
        for (int j = 0; j < 8; ++j) {
            const float left  = (j == 0) ? lf : gc[j - 1];
            const float right = (j == 7) ? rt : gc[j + 1];
            const float lap = gp[j] + gn[j] + left + right - 4.f * gc[j];
            s1 += lap;
            s2 += lap * lap;
            atomicAdd(&lh[w][(int)fminf(fmaxf(gc[j] * 255.f, 0.f), 255.f)], 1u);
        }

        if (d0.x > 0.f) { dnf += 1.f; dsf += d0.x; dqf += d0.x * d0.x; }
        if (d0.y > 0.f) { dnf += 1.f; dsf += d0.y; dqf += d0.y * d0.y; }
        if (d0.z > 0.f) { dnf += 1.f; dsf += d0.z; dqf += d0.z * d0.z; }
        if (d0.w > 0.f) { dnf += 1.f; dsf += d0.w; dqf += d0.w * d0.w; }
        if (d1.x > 0.f) { dnf += 1.f; dsf += d1.x; dqf += d1.x * d1.x; }
        if (d1.y > 0.f) { dnf += 1.f; dsf += d1.y; dqf += d1.y * d1.y; }
        if (d1.z > 0.f) { dnf += 1.f; dsf += d1.z; dqf += d1.z * d1.z; }
        if (d1.w > 0.f) { dnf += 1.f; dsf += d1.w; dqf += d1.w * d1.w; }

        #pragma unroll
        for (int j = 0; j < 8; ++j) { gp[j] = gc[j]; gc[j] = gn[j]; }
    }

    // block reduction of the 5 scalars
    double z0 = (double)s1, z1 = (double)s2, z2 = (double)dnf, z3 = (double)dsf, z4 = (double)dqf;
    for (int off = 32; off > 0; off >>= 1) {
        z0 += __shfl_down(z0, off, 64);
        z1 += __shfl_down(z1, off, 64);
        z2 += __shfl_down(z2, off, 64);
        z3 += __shfl_down(z3, off, 64);
        z4 += __shfl_down(z4, off, 64);
    }
    if (lane == 0) {
        red[w][0] = z0; red[w][1] = z1; red[w][2] = z2; red[w][3] = z3; red[w][4] = z4;
    }
    __syncthreads();   // covers lh writes and red[] writes

    const unsigned int hsum = lh[0][t] + lh[1][t] + lh[2][t] + lh[3][t];
    atomicAdd(&hist[b * 256 + t], hsum);
    if (t < 5) {
        const double v = red[0][t] + red[1][t] + red[2][t] + red[3][t];
        atomicAdd(&acc[t * 32 + b], v);
    }
}

__global__ __launch_bounds__(256) void final_kernel(
    const double* __restrict__ acc,
    const unsigned int* __restrict__ hist,
    float* __restrict__ out)
{
    __shared__ float part[256];
    const int t = threadIdx.x;
    const int b = t >> 3;        // 0..31
    const int sl = t & 7;        // 8 slices of 32 bins
    float e = 0.f;
    #pragma unroll
    for (int i = 0; i < 32; ++i) {
        const float p = (float)hist[b * 256 + sl * 32 + i] * (1.0f / (float)HW);
        e += p * log2f(p + 1e-4f);
    }
    part[t] = e;
    __syncthreads();

    if (t < NB) {
        float es = 0.f;
        #pragma unroll
        for (int i = 0; i < 8; ++i) es += part[t * 8 + i];
        const double entropy = -(double)es;
        const double N = (double)HW;

        const double ls = acc[t], lq = acc[32 + t];
        const double lvar = (lq - ls * ls / N) / (N - 1.0);
        const double clarity = lvar / (1000.0 + 1e-4);
        const double uniformity = 1.0 / (entropy + 1e-4);
        const double rgb_conf = 0.5 * (clarity + uniformity);

        const double n = acc[64 + t], sdep = acc[96 + t], q = acc[128 + t];
        const double mean = sdep / fmax(n, 1.0);
        const double sq = q - 2.0 * mean * sdep + mean * mean * n;
        const double var = sq / fmax(n - 1.0, 1.0);
        const double stdd = sqrt(fmax(var, 0.0));
        const double noise = (n > 0.0) ? stdd : 1.0;
        const double density = n / N;
        const double depth_conf = 0.5 * (density / (10000.0 + 1e-4) + 1.0 / (noise + 1e-4));

        const double denom = rgb_conf + depth_conf + 1e-4;
        out[t]      = (float)(rgb_conf / denom);
        out[NB + t] = (float)(depth_conf / denom);
    }
}

extern "C" void kernel_launch(void* const* d_in, const int* in_sizes, int n_in,
                              void* d_out, int out_size, void* d_ws, size_t ws_size,
                              hipStream_t stream) {
    const float* rgb   = (const float*)d_in[0];
    const float* depth = (const float*)d_in[1];
    float* out = (float*)d_out;

    double* acc = (double*)d_ws;
    unsigned int* hist = (unsigned int*)((char*)d_ws + ACC_DOUBLES * 8);

    hipMemsetAsync(d_ws, 0, WS_BYTES, stream);

    fused_kernel<<<dim3(STRIPS, NB), 256, 0, stream>>>(rgb, depth, acc, hist);
    final_kernel<<<1, 256, 0, stream>>>(acc, hist, out);
}